// Round 1
// baseline (1204.751 us; speedup 1.0000x reference)
//
#include <hip/hip_runtime.h>

#define TOK 4096
#define HID 1024
#define NEXP 8
#define CAP 512

#define BM 128
#define BN 128
#define BK 8

// ---------------------------------------------------------------------------
// Tiled f32 GEMM: C[M,N] = gather(A)[M,K] @ B_e[K,N] + bias_e
//  - rowmap != null: row m of the A-tile comes from A[rowmap[m]] (or zero if -1)
//  - expert batching: e = (m_tile_base)/rowsPerExpert selects B + e*bStride,
//    bias + e*biasStride. Dense GEMM: rowsPerExpert = M (e==0), strides 0.
// 256 threads, 128x128 tile, BK=8, 8x8 accumulator per thread.
// ---------------------------------------------------------------------------
__global__ __launch_bounds__(256, 2) void gemm_f32(
    const float* __restrict__ A, const float* __restrict__ B,
    const float* __restrict__ bias, float* __restrict__ C,
    int N, int K,
    const int* __restrict__ rowmap, int rowsPerExpert,
    long bStride, int biasStride)
{
  __shared__ float As[BK][BM];
  __shared__ float Bs[BK][BN];
  const int tid = threadIdx.x;
  const int bx = blockIdx.x, by = blockIdx.y;
  const int e = (by * BM) / rowsPerExpert;
  const float* Bp = B + (long)e * bStride + (long)(tid >> 5) * N + bx * BN + ((tid & 31) << 2);
  const float* biasp = bias + (long)e * biasStride + bx * BN;

  // A staging: thread -> (row ra, k-offset ka), loads float4
  const int ra = tid >> 1;
  const int ka = (tid & 1) << 2;
  const float* arow;
  bool azero = false;
  {
    int gm = by * BM + ra;
    if (rowmap) {
      int tok = rowmap[gm];
      if (tok < 0) { azero = true; arow = A; }
      else arow = A + (long)tok * K;
    } else {
      arow = A + (long)gm * K;
    }
  }

  float acc[8][8];
  #pragma unroll
  for (int i = 0; i < 8; ++i)
    #pragma unroll
    for (int j = 0; j < 8; ++j) acc[i][j] = 0.0f;

  const int tx = tid & 15, ty = tid >> 4;

  for (int k0 = 0; k0 < K; k0 += BK) {
    float4 av = azero ? make_float4(0.f,0.f,0.f,0.f)
                      : *(const float4*)(arow + k0 + ka);
    float4 bv = *(const float4*)(Bp + (long)k0 * N);
    __syncthreads();
    As[ka+0][ra] = av.x;
    As[ka+1][ra] = av.y;
    As[ka+2][ra] = av.z;
    As[ka+3][ra] = av.w;
    *(float4*)&Bs[tid >> 5][(tid & 31) << 2] = bv;
    __syncthreads();
    #pragma unroll
    for (int kk = 0; kk < BK; ++kk) {
      float a0[8], b0[8];
      *(float4*)(a0)     = *(const float4*)&As[kk][ty*4];
      *(float4*)(a0 + 4) = *(const float4*)&As[kk][ty*4 + 64];
      *(float4*)(b0)     = *(const float4*)&Bs[kk][tx*4];
      *(float4*)(b0 + 4) = *(const float4*)&Bs[kk][tx*4 + 64];
      #pragma unroll
      for (int i = 0; i < 8; ++i)
        #pragma unroll
        for (int j = 0; j < 8; ++j)
          acc[i][j] += a0[i] * b0[j];
    }
  }

  #pragma unroll
  for (int ih = 0; ih < 2; ++ih) {
    #pragma unroll
    for (int i = 0; i < 4; ++i) {
      int gr = by*BM + ih*64 + ty*4 + i;
      float* crow = C + (long)gr * N + bx * BN;
      #pragma unroll
      for (int jh = 0; jh < 2; ++jh) {
        int c0 = jh*64 + tx*4;
        float4 v;
        v.x = acc[ih*4+i][jh*4+0] + biasp[c0+0];
        v.y = acc[ih*4+i][jh*4+1] + biasp[c0+1];
        v.z = acc[ih*4+i][jh*4+2] + biasp[c0+2];
        v.w = acc[ih*4+i][jh*4+3] + biasp[c0+3];
        *(float4*)(crow + c0) = v;
      }
    }
  }
}

// ---------------------------------------------------------------------------
// Gating: logits = act[t] @ wg (H x 8), softmax, argmax.
// One block per token. Writes idx[t] (argmax expert) and gmax[t] (its prob).
// ---------------------------------------------------------------------------
__global__ __launch_bounds__(256) void gate_kernel(
    const float* __restrict__ act, const float* __restrict__ wg,
    int* __restrict__ idx, float* __restrict__ gmax)
{
  __shared__ float part[256][NEXP];
  const int t = blockIdx.x;
  const float* row = act + (long)t * HID;
  float p[NEXP];
  #pragma unroll
  for (int e = 0; e < NEXP; ++e) p[e] = 0.0f;
  for (int h = threadIdx.x; h < HID; h += 256) {
    float xv = row[h];
    const float* wrow = wg + h * NEXP;
    #pragma unroll
    for (int e = 0; e < NEXP; ++e) p[e] += xv * wrow[e];
  }
  #pragma unroll
  for (int e = 0; e < NEXP; ++e) part[threadIdx.x][e] = p[e];
  __syncthreads();
  for (int s = 128; s > 0; s >>= 1) {
    if (threadIdx.x < s) {
      #pragma unroll
      for (int e = 0; e < NEXP; ++e)
        part[threadIdx.x][e] += part[threadIdx.x + s][e];
    }
    __syncthreads();
  }
  if (threadIdx.x == 0) {
    float m = part[0][0]; int am = 0;
    #pragma unroll
    for (int e = 1; e < NEXP; ++e)
      if (part[0][e] > m) { m = part[0][e]; am = e; }
    float s = 0.0f;
    #pragma unroll
    for (int e = 0; e < NEXP; ++e) s += expf(part[0][e] - m);
    idx[t] = am;
    gmax[t] = 1.0f / s;   // softmax prob of the argmax expert
  }
}

// ---------------------------------------------------------------------------
// Capacity scan: per-expert ordered prefix over token index (== cumsum of
// one_hot in the reference). One block, 8 waves, wave e handles expert e.
// Writes loc[t] (slot in expert queue or -1 if dropped) and rowmap[e*CAP+c]
// (token occupying slot c, -1 if empty).
// ---------------------------------------------------------------------------
__global__ __launch_bounds__(512) void scan_kernel(
    const int* __restrict__ idx, int* __restrict__ loc, int* __restrict__ rowmap)
{
  const int tid = threadIdx.x;
  for (int i = tid; i < NEXP * CAP; i += 512) rowmap[i] = -1;
  __syncthreads();
  const int wave = tid >> 6, lane = tid & 63;
  int running = 0;
  for (int c = 0; c < TOK / 64; ++c) {
    int t = c * 64 + lane;
    bool flag = (idx[t] == wave);
    unsigned long long m = __ballot(flag);
    int pos = running + __popcll(m & ((1ull << lane) - 1ull));
    if (flag) {
      if (pos < CAP) { loc[t] = pos; rowmap[wave * CAP + pos] = t; }
      else loc[t] = -1;
    }
    running += __popcll(m);
  }
}

// ---------------------------------------------------------------------------
// Combine: out[t] = gate * h2[idx[t]*CAP + loc[t]]  (or 0 if dropped)
// ---------------------------------------------------------------------------
__global__ __launch_bounds__(256) void combine_kernel(
    const float* __restrict__ h2, const int* __restrict__ idx,
    const int* __restrict__ loc, const float* __restrict__ gmax,
    float* __restrict__ out)
{
  const int t = blockIdx.x;
  const int l = loc[t];
  float4* o = (float4*)(out + (long)t * HID);
  if (l >= 0) {
    float g = gmax[t];
    const float4* src = (const float4*)(h2 + ((long)idx[t] * CAP + l) * HID);
    for (int i = threadIdx.x; i < HID / 4; i += 256) {
      float4 v = src[i];
      o[i] = make_float4(g * v.x, g * v.y, g * v.z, g * v.w);
    }
  } else {
    for (int i = threadIdx.x; i < HID / 4; i += 256)
      o[i] = make_float4(0.f, 0.f, 0.f, 0.f);
  }
}

// ---------------------------------------------------------------------------
// sent[b][h] = mean_s (a[b,s,h] + c[b,s,h])
// ---------------------------------------------------------------------------
__global__ __launch_bounds__(256) void mean_kernel(
    const float* __restrict__ a, const float* __restrict__ c,
    float* __restrict__ sent)
{
  const int h = blockIdx.x * 256 + threadIdx.x;
  const int b = blockIdx.y;
  const float* pa = a + (long)b * 512 * HID + h;
  const float* pc = c + (long)b * 512 * HID + h;
  float acc = 0.0f;
  for (int s = 0; s < 512; ++s) acc += pa[(long)s * HID] + pc[(long)s * HID];
  sent[b * HID + h] = acc * (1.0f / 512.0f);
}

// ---------------------------------------------------------------------------
// loss = -mean_b log_softmax(sent[b])[y[b]]   (single block, 1024 threads)
// ---------------------------------------------------------------------------
__global__ __launch_bounds__(1024) void loss_kernel(
    const float* __restrict__ sent, const int* __restrict__ y,
    float* __restrict__ out)
{
  __shared__ float red[1024];
  float loss = 0.0f;
  for (int b = 0; b < 8; ++b) {
    float v = sent[b * HID + threadIdx.x];
    red[threadIdx.x] = v;
    __syncthreads();
    for (int s = 512; s > 0; s >>= 1) {
      if (threadIdx.x < s)
        red[threadIdx.x] = fmaxf(red[threadIdx.x], red[threadIdx.x + s]);
      __syncthreads();
    }
    float m = red[0];
    __syncthreads();
    red[threadIdx.x] = expf(v - m);
    __syncthreads();
    for (int s = 512; s > 0; s >>= 1) {
      if (threadIdx.x < s) red[threadIdx.x] += red[threadIdx.x + s];
      __syncthreads();
    }
    if (threadIdx.x == 0) {
      float lse = m + logf(red[0]);
      loss += -(sent[b * HID + y[b]] - lse);
    }
    __syncthreads();
  }
  if (threadIdx.x == 0) out[0] = loss * (1.0f / 8.0f);
}

// ---------------------------------------------------------------------------
extern "C" void kernel_launch(void* const* d_in, const int* in_sizes, int n_in,
                              void* d_out, int out_size, void* d_ws, size_t ws_size,
                              hipStream_t stream)
{
  const float* x    = (const float*)d_in[0];
  const int*   y    = (const int*)d_in[1];
  const float* w1   = (const float*)d_in[2];
  const float* b1   = (const float*)d_in[3];
  const float* w2   = (const float*)d_in[4];
  const float* b2   = (const float*)d_in[5];
  const float* w3   = (const float*)d_in[6];
  const float* b3   = (const float*)d_in[7];
  const float* wg1  = (const float*)d_in[8];
  const float* e1w1 = (const float*)d_in[9];
  const float* e1b1 = (const float*)d_in[10];
  const float* e1w2 = (const float*)d_in[11];
  const float* e1b2 = (const float*)d_in[12];
  const float* wg2  = (const float*)d_in[13];
  const float* e2w1 = (const float*)d_in[14];
  const float* e2b1 = (const float*)d_in[15];
  const float* e2w2 = (const float*)d_in[16];
  const float* e2b2 = (const float*)d_in[17];

  float* ws = (float*)d_ws;
  float* hidden = ws;                       // [TOK, HID]
  float* X1     = ws + (long)4 * 1024 * 1024; // [TOK, HID]
  float* X2     = ws + (long)8 * 1024 * 1024; // [TOK, HID]
  float* gmax   = ws + (long)12 * 1024 * 1024;
  int*   idx    = (int*)(gmax + TOK);
  int*   loc    = idx + TOK;
  int*   rowmap = loc + TOK;
  float* sent   = (float*)(rowmap + NEXP * CAP);

  dim3 gg(HID / BN, TOK / BM);
  const long wStride = (long)HID * HID;

  // hidden = x @ w1 + b1
  gemm_f32<<<gg, 256, 0, stream>>>(x, w1, b1, hidden, HID, HID, nullptr, TOK, 0, 0);

  // ---- MoE layer 1 ----
  gate_kernel<<<TOK, 256, 0, stream>>>(hidden, wg1, idx, gmax);
  scan_kernel<<<1, 512, 0, stream>>>(idx, loc, rowmap);
  gemm_f32<<<gg, 256, 0, stream>>>(hidden, e1w1, e1b1, X1, HID, HID, rowmap, CAP, wStride, HID);
  gemm_f32<<<gg, 256, 0, stream>>>(X1, e1w2, e1b2, X2, HID, HID, nullptr, CAP, wStride, HID);
  combine_kernel<<<TOK, 256, 0, stream>>>(X2, idx, loc, gmax, X1);

  // out = moe1 @ w2 + b2
  gemm_f32<<<gg, 256, 0, stream>>>(X1, w2, b2, X2, HID, HID, nullptr, TOK, 0, 0);

  // ---- MoE layer 2 ----
  gate_kernel<<<TOK, 256, 0, stream>>>(X2, wg2, idx, gmax);
  scan_kernel<<<1, 512, 0, stream>>>(idx, loc, rowmap);
  gemm_f32<<<gg, 256, 0, stream>>>(X2, e2w1, e2b1, X1, HID, HID, rowmap, CAP, wStride, HID);
  gemm_f32<<<gg, 256, 0, stream>>>(X1, e2w2, e2b2, X2, HID, HID, nullptr, CAP, wStride, HID);
  combine_kernel<<<TOK, 256, 0, stream>>>(X2, idx, loc, gmax, X1);

  // out = moe2 @ w3 + b3
  gemm_f32<<<gg, 256, 0, stream>>>(X1, w3, b3, X2, HID, HID, nullptr, TOK, 0, 0);

  // final: sent = mean_s(hidden + out), loss = NLL(log_softmax(sent), y)
  mean_kernel<<<dim3(HID / 256, 8), 256, 0, stream>>>(hidden, X2, sent);
  loss_kernel<<<1, 1024, 0, stream>>>(sent, y, (float*)d_out);
}

// Round 2
// 279.015 us; speedup vs baseline: 4.3179x; 4.3179x over previous
//
#include <hip/hip_runtime.h>

#define TOK 4096
#define HID 1024
#define NEXP 8
#define CAP 512

typedef _Float16 f16;
typedef f16 f16x8 __attribute__((ext_vector_type(8)));
typedef f16 f16x4 __attribute__((ext_vector_type(4)));
typedef float f32x4 __attribute__((ext_vector_type(4)));

typedef const __attribute__((address_space(1))) void gvoid;
typedef __attribute__((address_space(3))) void lvoid;

__device__ __forceinline__ void gld16(const void* g, void* l) {
  __builtin_amdgcn_global_load_lds((gvoid*)g, (lvoid*)l, 16, 0, 0);
}

// ---------------------------------------------------------------------------
// MFMA f16 GEMM: C[M=4096,N=1024] = gather(A)[.,K=1024] @ Bt_e^T + bias_e
//   A:  [rows][1024] f16 row-major (rowmap gathers rows; -1 -> zero row TOK)
//   Bt: [e][N=1024][K=1024] f16 (pre-transposed weights)
// Tile 64x128, BK=64, 4 waves (each wave: 64 rows x 32 cols = 4x2 frags).
// LDS rows are 128B with XOR chunk swizzle (chunk ^= row&7) applied via
// pre-swizzled global source (global_load_lds writes linearly).
// ---------------------------------------------------------------------------
#define BM 64
#define BN 128
#define BK 64

__global__ __launch_bounds__(256, 2) void gemm_h(
    const f16* __restrict__ A, const f16* __restrict__ Bt,
    const float* __restrict__ bias,
    float* __restrict__ Cf, f16* __restrict__ Ch,
    const int* __restrict__ rowmap, int rowsPerExpert,
    long bStride, int biasStride)
{
  __shared__ f16 As[BM * BK];   // [64 rows][64 k]
  __shared__ f16 Bs[BN * BK];   // [128 n-rows][64 k]

  const int tid = threadIdx.x;
  const int w = tid >> 6, l = tid & 63;
  const int bx = blockIdx.x, by = blockIdx.y;
  const int e = (by * BM) / rowsPerExpert;

  // ---- staging setup (per-lane global sources, linear LDS dests) ----
  const int lr = l >> 3;                       // row within 8-row inst
  const int chunkSw = ((l & 7) ^ lr) * 8;      // swizzled k-chunk (f16 elems)

  long tokA0, tokA1;
  {
    int r0 = by * BM + w * 16 + lr, r1 = r0 + 8;
    if (rowmap) {
      int t0 = rowmap[r0], t1 = rowmap[r1];
      tokA0 = (t0 < 0) ? (long)TOK : t0;
      tokA1 = (t1 < 0) ? (long)TOK : t1;
    } else { tokA0 = r0; tokA1 = r1; }
  }
  const f16* pa0 = A + tokA0 * HID + chunkSw;
  const f16* pa1 = A + tokA1 * HID + chunkSw;
  const f16* pb  = Bt + (size_t)e * bStride
                 + ((size_t)(bx * BN + w * 32 + lr)) * HID + chunkSw;

  f16* adst0 = As + (w * 16) * BK;
  f16* adst1 = As + (w * 16 + 8) * BK;
  f16* bdst0 = Bs + (w * 32) * BK;
  f16* bdst1 = Bs + (w * 32 + 8) * BK;
  f16* bdst2 = Bs + (w * 32 + 16) * BK;
  f16* bdst3 = Bs + (w * 32 + 24) * BK;

  f32x4 acc[4][2];
  #pragma unroll
  for (int i = 0; i < 4; ++i)
    #pragma unroll
    for (int j = 0; j < 2; ++j) acc[i][j] = (f32x4){0.f, 0.f, 0.f, 0.f};

  const int g = l >> 4, c = l & 15;
  const int sa = c & 7;

  for (int k0 = 0; k0 < HID; k0 += BK) {
    __syncthreads();                       // previous compute done
    gld16(pa0 + k0, adst0);
    gld16(pa1 + k0, adst1);
    gld16(pb + k0,            bdst0);
    gld16(pb + 8  * HID + k0, bdst1);
    gld16(pb + 16 * HID + k0, bdst2);
    gld16(pb + 24 * HID + k0, bdst3);
    __syncthreads();                       // compiler drains vmcnt before barrier

    #pragma unroll
    for (int h = 0; h < 2; ++h) {
      f16x8 af[4], bf[2];
      const int q = ((h * 4 + g) ^ sa) * 8;
      #pragma unroll
      for (int mi = 0; mi < 4; ++mi)
        af[mi] = *(const f16x8*)&As[(mi * 16 + c) * BK + q];
      #pragma unroll
      for (int ni = 0; ni < 2; ++ni)
        bf[ni] = *(const f16x8*)&Bs[(w * 32 + ni * 16 + c) * BK + q];
      #pragma unroll
      for (int mi = 0; mi < 4; ++mi)
        #pragma unroll
        for (int ni = 0; ni < 2; ++ni)
          acc[mi][ni] = __builtin_amdgcn_mfma_f32_16x16x32_f16(
              af[mi], bf[ni], acc[mi][ni], 0, 0, 0);
    }
  }

  // ---- epilogue: D col = lane&15, row = (lane>>4)*4 + reg ----
  #pragma unroll
  for (int ni = 0; ni < 2; ++ni) {
    const int col = bx * BN + w * 32 + ni * 16 + c;
    const float bv = bias[(size_t)e * biasStride + col];
    #pragma unroll
    for (int mi = 0; mi < 4; ++mi) {
      #pragma unroll
      for (int rr = 0; rr < 4; ++rr) {
        const int row = by * BM + mi * 16 + g * 4 + rr;
        const float v = acc[mi][ni][rr] + bv;
        if (Cf) Cf[(size_t)row * HID + col] = v;
        if (Ch) Ch[(size_t)row * HID + col] = (f16)v;
      }
    }
  }
}

// ---------------------------------------------------------------------------
// Transpose-cast: src [z][1024 k][1024 n] f32  ->  dst [z][1024 n][1024 k] f16
// ---------------------------------------------------------------------------
__global__ __launch_bounds__(256) void tcast(const float* __restrict__ src,
                                             f16* __restrict__ dst)
{
  __shared__ float t[64][65];
  const int tid = threadIdx.x;
  const long base = (long)blockIdx.z * HID * HID;
  const int kb = blockIdx.y * 64, nb = blockIdx.x * 64;
  const int r = tid >> 4, c4 = (tid & 15) * 4;
  #pragma unroll
  for (int p = 0; p < 4; ++p) {
    float4 v = *(const float4*)&src[base + (long)(kb + p * 16 + r) * HID + nb + c4];
    t[p * 16 + r][c4 + 0] = v.x;
    t[p * 16 + r][c4 + 1] = v.y;
    t[p * 16 + r][c4 + 2] = v.z;
    t[p * 16 + r][c4 + 3] = v.w;
  }
  __syncthreads();
  #pragma unroll
  for (int p = 0; p < 4; ++p) {
    int n = p * 16 + r;
    f16x4 o = {(f16)t[c4 + 0][n], (f16)t[c4 + 1][n],
               (f16)t[c4 + 2][n], (f16)t[c4 + 3][n]};
    *(f16x4*)&dst[base + (long)(nb + n) * HID + kb + c4] = o;
  }
}

// ---------------------------------------------------------------------------
__global__ void castx(const float* __restrict__ src, f16* __restrict__ dst) {
  int i = blockIdx.x * 256 + threadIdx.x;
  float4 v = *(const float4*)&src[(size_t)i * 4];
  f16x4 o = {(f16)v.x, (f16)v.y, (f16)v.z, (f16)v.w};
  *(f16x4*)&dst[(size_t)i * 4] = o;
}

__global__ void zpad(f16* p) {
  ((f16x4*)p)[threadIdx.x] = (f16x4){0, 0, 0, 0};
}

// ---------------------------------------------------------------------------
__global__ __launch_bounds__(256) void gate_kernel(
    const float* __restrict__ act, const float* __restrict__ wg,
    int* __restrict__ idx, float* __restrict__ gmax)
{
  __shared__ float part[256][NEXP];
  const int t = blockIdx.x;
  const float* row = act + (long)t * HID;
  float p[NEXP];
  #pragma unroll
  for (int e = 0; e < NEXP; ++e) p[e] = 0.0f;
  for (int h = threadIdx.x; h < HID; h += 256) {
    float xv = row[h];
    const float* wrow = wg + h * NEXP;
    #pragma unroll
    for (int e = 0; e < NEXP; ++e) p[e] += xv * wrow[e];
  }
  #pragma unroll
  for (int e = 0; e < NEXP; ++e) part[threadIdx.x][e] = p[e];
  __syncthreads();
  for (int s = 128; s > 0; s >>= 1) {
    if (threadIdx.x < s) {
      #pragma unroll
      for (int e = 0; e < NEXP; ++e)
        part[threadIdx.x][e] += part[threadIdx.x + s][e];
    }
    __syncthreads();
  }
  if (threadIdx.x == 0) {
    float m = part[0][0]; int am = 0;
    #pragma unroll
    for (int e = 1; e < NEXP; ++e)
      if (part[0][e] > m) { m = part[0][e]; am = e; }
    float s = 0.0f;
    #pragma unroll
    for (int e = 0; e < NEXP; ++e) s += expf(part[0][e] - m);
    idx[t] = am;
    gmax[t] = 1.0f / s;
  }
}

// ---------------------------------------------------------------------------
__global__ __launch_bounds__(512) void scan_kernel(
    const int* __restrict__ idx, int* __restrict__ loc, int* __restrict__ rowmap)
{
  __shared__ int sidx[TOK];
  const int tid = threadIdx.x;
  for (int i = tid; i < TOK; i += 512) sidx[i] = idx[i];
  for (int i = tid; i < NEXP * CAP; i += 512) rowmap[i] = -1;
  __syncthreads();
  const int wave = tid >> 6, lane = tid & 63;
  int running = 0;
  for (int ch = 0; ch < TOK / 64; ++ch) {
    int t = ch * 64 + lane;
    bool flag = (sidx[t] == wave);
    unsigned long long m = __ballot(flag);
    int pos = running + __popcll(m & ((1ull << lane) - 1ull));
    if (flag) {
      if (pos < CAP) { loc[t] = pos; rowmap[wave * CAP + pos] = t; }
      else loc[t] = -1;
    }
    running += __popcll(m);
  }
}

// ---------------------------------------------------------------------------
__global__ __launch_bounds__(256) void combine_kernel(
    const float* __restrict__ h2, const int* __restrict__ idx,
    const int* __restrict__ loc, const float* __restrict__ gmax,
    f16* __restrict__ out)
{
  const int t = blockIdx.x;
  const int lcc = loc[t];
  f16x4* o = (f16x4*)(out + (size_t)t * HID);
  if (lcc >= 0) {
    float gv = gmax[t];
    const float4* src = (const float4*)(h2 + ((size_t)idx[t] * CAP + lcc) * HID);
    for (int i = threadIdx.x; i < HID / 4; i += 256) {
      float4 v = src[i];
      o[i] = (f16x4){(f16)(gv * v.x), (f16)(gv * v.y),
                     (f16)(gv * v.z), (f16)(gv * v.w)};
    }
  } else {
    for (int i = threadIdx.x; i < HID / 4; i += 256)
      o[i] = (f16x4){0, 0, 0, 0};
  }
}

// ---------------------------------------------------------------------------
__global__ __launch_bounds__(256) void mean_kernel(
    const float* __restrict__ a, const float* __restrict__ c,
    float* __restrict__ sent)
{
  const int h = blockIdx.x * 256 + threadIdx.x;
  const int b = blockIdx.y;
  const float* pa = a + (long)b * 512 * HID + h;
  const float* pc = c + (long)b * 512 * HID + h;
  float acc = 0.0f;
  for (int s = 0; s < 512; ++s) acc += pa[(long)s * HID] + pc[(long)s * HID];
  sent[b * HID + h] = acc * (1.0f / 512.0f);
}

__global__ __launch_bounds__(1024) void loss_kernel(
    const float* __restrict__ sent, const int* __restrict__ y,
    float* __restrict__ out)
{
  __shared__ float red[1024];
  float loss = 0.0f;
  for (int b = 0; b < 8; ++b) {
    float v = sent[b * HID + threadIdx.x];
    red[threadIdx.x] = v;
    __syncthreads();
    for (int s = 512; s > 0; s >>= 1) {
      if (threadIdx.x < s)
        red[threadIdx.x] = fmaxf(red[threadIdx.x], red[threadIdx.x + s]);
      __syncthreads();
    }
    float m = red[0];
    __syncthreads();
    red[threadIdx.x] = expf(v - m);
    __syncthreads();
    for (int s = 512; s > 0; s >>= 1) {
      if (threadIdx.x < s) red[threadIdx.x] += red[threadIdx.x + s];
      __syncthreads();
    }
    if (threadIdx.x == 0) {
      float lse = m + logf(red[0]);
      loss += -(sent[b * HID + y[b]] - lse);
    }
    __syncthreads();
  }
  if (threadIdx.x == 0) out[0] = loss * (1.0f / 8.0f);
}

// ---------------------------------------------------------------------------
extern "C" void kernel_launch(void* const* d_in, const int* in_sizes, int n_in,
                              void* d_out, int out_size, void* d_ws, size_t ws_size,
                              hipStream_t stream)
{
  const float* x    = (const float*)d_in[0];
  const int*   y    = (const int*)d_in[1];
  const float* w1   = (const float*)d_in[2];
  const float* b1   = (const float*)d_in[3];
  const float* w2   = (const float*)d_in[4];
  const float* b2   = (const float*)d_in[5];
  const float* w3   = (const float*)d_in[6];
  const float* b3   = (const float*)d_in[7];
  const float* wg1  = (const float*)d_in[8];
  const float* e1w1 = (const float*)d_in[9];
  const float* e1b1 = (const float*)d_in[10];
  const float* e1w2 = (const float*)d_in[11];
  const float* e1b2 = (const float*)d_in[12];
  const float* wg2  = (const float*)d_in[13];
  const float* e2w1 = (const float*)d_in[14];
  const float* e2b1 = (const float*)d_in[15];
  const float* e2w2 = (const float*)d_in[16];
  const float* e2b2 = (const float*)d_in[17];

  // workspace layout (~64 MB)
  float* F32_A = (float*)d_ws;                       // 4096x1024 f32 (hidden)
  float* F32_B = F32_A + 4194304;                    // 4096x1024 f32 (rotating)
  f16*   WT    = (f16*)(F32_B + 4194304);            // 8x1024x1024 f16 (weightT slot)
  f16*   H16A  = WT + 8388608;                       // 4096x1024 f16
  f16*   H16B  = H16A + 4194304;                     // 4097x1024 f16 (gather src + pad)
  float* gmax  = (float*)(H16B + 4195328);
  int*   idx    = (int*)(gmax + TOK);
  int*   loc    = idx + TOK;
  int*   rowmap = loc + TOK;
  float* sent   = (float*)(rowmap + NEXP * CAP);

  const long EW = (long)HID * HID;  // expert weight stride (elements)
  dim3 gg(HID / BN, TOK / BM);
  dim3 tg1(16, 16, 1), tg8(16, 16, 8);

  zpad<<<1, 256, 0, stream>>>(H16B + (size_t)TOK * HID);
  castx<<<4096, 256, 0, stream>>>(x, H16A);

  // hidden = x @ w1 + b1
  tcast<<<tg1, 256, 0, stream>>>(w1, WT);
  gemm_h<<<gg, 256, 0, stream>>>(H16A, WT, b1, F32_A, H16B, nullptr, TOK, 0, 0);

  // ---- MoE layer 1 ----
  gate_kernel<<<TOK, 256, 0, stream>>>(F32_A, wg1, idx, gmax);
  scan_kernel<<<1, 512, 0, stream>>>(idx, loc, rowmap);
  tcast<<<tg8, 256, 0, stream>>>(e1w1, WT);
  gemm_h<<<gg, 256, 0, stream>>>(H16B, WT, e1b1, nullptr, H16A, rowmap, CAP, EW, HID);
  tcast<<<tg8, 256, 0, stream>>>(e1w2, WT);
  gemm_h<<<gg, 256, 0, stream>>>(H16A, WT, e1b2, F32_B, nullptr, nullptr, CAP, EW, HID);
  combine_kernel<<<TOK, 256, 0, stream>>>(F32_B, idx, loc, gmax, H16A);

  // out = moe1 @ w2 + b2
  tcast<<<tg1, 256, 0, stream>>>(w2, WT);
  gemm_h<<<gg, 256, 0, stream>>>(H16A, WT, b2, F32_B, H16B, nullptr, TOK, 0, 0);

  // ---- MoE layer 2 ----
  gate_kernel<<<TOK, 256, 0, stream>>>(F32_B, wg2, idx, gmax);
  scan_kernel<<<1, 512, 0, stream>>>(idx, loc, rowmap);
  tcast<<<tg8, 256, 0, stream>>>(e2w1, WT);
  gemm_h<<<gg, 256, 0, stream>>>(H16B, WT, e2b1, nullptr, H16A, rowmap, CAP, EW, HID);
  tcast<<<tg8, 256, 0, stream>>>(e2w2, WT);
  gemm_h<<<gg, 256, 0, stream>>>(H16A, WT, e2b2, F32_B, nullptr, nullptr, CAP, EW, HID);
  combine_kernel<<<TOK, 256, 0, stream>>>(F32_B, idx, loc, gmax, H16A);

  // out = moe2 @ w3 + b3
  tcast<<<tg1, 256, 0, stream>>>(w3, WT);
  gemm_h<<<gg, 256, 0, stream>>>(H16A, WT, b3, F32_B, nullptr, nullptr, TOK, 0, 0);

  // final reduction
  mean_kernel<<<dim3(HID / 256, 8), 256, 0, stream>>>(F32_A, F32_B, sent);
  loss_kernel<<<1, 1024, 0, stream>>>(sent, y, (float*)d_out);
}